// Round 7
// baseline (981.271 us; speedup 1.0000x reference)
//
#include <hip/hip_runtime.h>
#include <stdint.h>
#include <stddef.h>

// WanSelfAttention on gfx950.
// R5: XOR chunk-swizzle on LDS tiles (global-source permutation at staging).
// R6: T5 s_setprio around pure-MFMA clusters in k_attn.
// R7: k_attn 3-barrier pipeline with counted vmcnt; T13 defer-max; vec rope/vt.
// R9: swapped-operand QK^T in k_attn -> one-pass per-lane softmax. 8 waves.
// R11: k_gemm 256x256 8-phase (T3+T4), 128KB LDS dbuf.
// R12: k_gemm deepened wait algebra: stages pushed 3-6 phases ahead of use
//      (q0->Bq1(t+1), q1->Aq1(t+1), q2->Aq0(t+2), q3->Bq0(t+2)), vmcnt(6)
//      only at q1/q3 (every wait targets >=3-phase-old loads ~ HBM latency),
//      ONE barrier per phase (was 2). Prologue 6 half-tiles + vmcnt(6);
//      tail drains 6->4->2->0. Retirement chain verified per-phase.

typedef __attribute__((ext_vector_type(8))) short short8;
typedef __attribute__((ext_vector_type(4))) float f32x4;
typedef __attribute__((ext_vector_type(4))) unsigned short ushort4v;
typedef __attribute__((address_space(1))) uint32_t gu32;
typedef __attribute__((address_space(3))) uint32_t lu32;

__device__ __forceinline__ float btof(unsigned short u){
  union { float f; uint32_t i; } x; x.i = ((uint32_t)u) << 16; return x.f;
}
__device__ __forceinline__ unsigned short ftob(float f){
  uint32_t u = __builtin_bit_cast(uint32_t, f);
  u += 0x7fffu + ((u >> 16) & 1u);   // RTNE (finite inputs only)
  return (unsigned short)(u >> 16);
}
__device__ __forceinline__ float rb(float f){ return btof(ftob(f)); }

__device__ __forceinline__ void async_cp16(const void* g, void* l){
  __builtin_amdgcn_global_load_lds((gu32*)g, (lu32*)l, 16, 0, 0);
}

__device__ __forceinline__ void barrier_raw(){
  asm volatile("" ::: "memory");
  __builtin_amdgcn_s_barrier();
  asm volatile("" ::: "memory");
}

__device__ __forceinline__ f32x4 vmax4(f32x4 a, f32x4 b){
  f32x4 r;
  r[0] = fmaxf(a[0], b[0]); r[1] = fmaxf(a[1], b[1]);
  r[2] = fmaxf(a[2], b[2]); r[3] = fmaxf(a[3], b[3]);
  return r;
}

#define VMW6 asm volatile("s_waitcnt vmcnt(6)" ::: "memory")
#define VMW4 asm volatile("s_waitcnt vmcnt(4)" ::: "memory")
#define VMW2 asm volatile("s_waitcnt vmcnt(2)" ::: "memory")
#define VMW0 asm volatile("s_waitcnt vmcnt(0)" ::: "memory")

// ---------------- converters ----------------

__global__ __launch_bounds__(256) void k_convert_x(const float* __restrict__ x,
                                                   unsigned short* __restrict__ xb){
  int i = (blockIdx.x * 256 + threadIdx.x) * 4;
  float4 v = *(const float4*)(x + i);
  ushort4v o = { ftob(v.x), ftob(v.y), ftob(v.z), ftob(v.w) };
  *(ushort4v*)(xb + i) = o;
}

__global__ __launch_bounds__(256) void k_bias(const float* __restrict__ bq,
                                              const float* __restrict__ bk,
                                              const float* __restrict__ bv,
                                              float* __restrict__ bias9){
  int i = blockIdx.x * 256 + threadIdx.x;     // 0..9215
  const float* s = (i < 3072) ? bq : ((i < 6144) ? bk : bv);
  bias9[i] = s[i % 3072];
}

// Transpose f32 weights (K x N, row-major) into bf16 W^T (N x K) rows.
__global__ __launch_bounds__(256) void k_wt(const float* __restrict__ wq,
                                            const float* __restrict__ wk,
                                            const float* __restrict__ wv,
                                            const float* __restrict__ wo,
                                            unsigned short* __restrict__ WTqkv,
                                            unsigned short* __restrict__ woT){
  __shared__ float tile[64][65];
  int k0 = blockIdx.x * 64;
  int n0g = blockIdx.y * 64;
  const float* src; unsigned short* dst; int col0, drow0;
  if (n0g < 9216){
    int sel = n0g / 3072;
    src = (sel == 0) ? wq : ((sel == 1) ? wk : wv);
    col0 = n0g % 3072; dst = WTqkv; drow0 = n0g;
  } else { src = wo; col0 = n0g - 9216; dst = woT; drow0 = n0g - 9216; }
  for (int i = 0; i < 16; i++){
    int idx = i * 256 + threadIdx.x;
    int r = idx >> 6, c = idx & 63;
    tile[r][c] = src[(size_t)(k0 + r) * 3072 + col0 + c];
  }
  __syncthreads();
  for (int i = 0; i < 16; i++){
    int idx = i * 256 + threadIdx.x;
    int rr = idx >> 6, cc = idx & 63;
    dst[(size_t)(drow0 + rr) * 3072 + k0 + cc] = ftob(tile[cc][rr]);
  }
}

// ---------------- GEMM 256x256, BK=64, 8 waves, 4-phase deep pipeline ------
// LDS (dynamic 128KB): A[2][128 rows x 256B], B[2][128 rows x 256B]; LDS row j
// holds matrix rows 2j,2j+1 as 16x16B chunks, phys = lc ^ (j&15).
// Phase layout: [ds_read frags | stage 1 half-tile | {vmcnt(6) @q1,q3} |
// barrier | setprio1 16xMFMA setprio0]. Stage targets: q0->Bq1(t+1),
// q1->Aq1(t+1), q2->Aq0(t+2) (curr buf, its q0-half consumed 2 phases ago),
// q3->Bq0(t+2). Every vm-wait targets loads issued >=3 phases earlier.
template <bool OUT_BF16>
__global__ __launch_bounds__(512, 2) void k_gemm(const unsigned short* __restrict__ A,
                                                 const unsigned short* __restrict__ BT,
                                                 const float* __restrict__ bias,
                                                 void* __restrict__ Cout, int N, int K){
  extern __shared__ unsigned short lds[];
  unsigned short* AsL = lds;              // [2][16384]
  unsigned short* BsL = lds + 32768;      // [2][16384]

  int tid = threadIdx.x;
  int w = tid >> 6, lane = tid & 63;
  int quad = lane >> 4, l16 = lane & 15;
  int wr = w >> 2, wc = w & 3;            // wave tile: rows wr*128, cols wc*64
  int m0 = blockIdx.y * 256, n0 = blockIdx.x * 256;

  f32x4 acc[8][4] = {};
  short8 af[4][2], b0[2][2], b1[2][2];

  auto lda = [&](const unsigned short* base, int mh){
#pragma unroll
    for (int im = 0; im < 4; im++)
#pragma unroll
      for (int kk = 0; kk < 2; kk++){
        int j = wr * 64 + mh * 32 + im * 8 + (l16 >> 1);
        int lc = ((l16 & 1) << 3) | (kk << 2) | quad;
        af[im][kk] = *(const short8*)(base + j * 128 + (lc ^ (j & 15)) * 8);
      }
  };
  auto ldb = [&](const unsigned short* base, short8 (&bb)[2][2], int nh){
#pragma unroll
    for (int in = 0; in < 2; in++)
#pragma unroll
      for (int kk = 0; kk < 2; kk++){
        int j = wc * 32 + nh * 16 + in * 8 + (l16 >> 1);
        int lc = ((l16 & 1) << 3) | (kk << 2) | quad;
        bb[in][kk] = *(const short8*)(base + j * 128 + (lc ^ (j & 15)) * 8);
      }
  };
  auto mfmaQ = [&](int mh, short8 (&bb)[2][2], int nh){
    __builtin_amdgcn_s_setprio(1);
#pragma unroll
    for (int im = 0; im < 4; im++)
#pragma unroll
      for (int in = 0; in < 2; in++)
#pragma unroll
        for (int kk = 0; kk < 2; kk++)
          acc[mh * 4 + im][nh * 2 + in] =
            __builtin_amdgcn_mfma_f32_16x16x32_bf16(af[im][kk], bb[in][kk],
                                                    acc[mh * 4 + im][nh * 2 + in], 0, 0, 0);
    __builtin_amdgcn_s_setprio(0);
  };

  // staging: one half-tile = 16KB = 2 ops/wave; LDS dest linear (wave-uniform
  // base), per-lane GLOBAL source pre-swizzled (both-sides-or-neither rule).
  auto stageA = [&](unsigned short* dst, int kt, int mh){
#pragma unroll
    for (int i = 0; i < 2; i++){
      int idx0 = (w * 2 + i) * 8;
      int mr0 = (((idx0 >> 6) << 7) | (idx0 & 63)) | (mh << 6);
      int jb = mr0 >> 1;                  // 4 LDS rows per op
      int j = jb + (lane >> 4);
      int lc = (lane & 15) ^ (j & 15);
      int mr = (j << 1) + (lc >> 3);
      async_cp16(A + (size_t)(m0 + mr) * K + kt + (lc & 7) * 8, dst + jb * 128);
    }
  };
  auto stageB = [&](unsigned short* dst, int kt, int nh){
#pragma unroll
    for (int i = 0; i < 2; i++){
      int idx0 = (w * 2 + i) * 8;
      int nr0 = (((idx0 >> 5) << 6) | (idx0 & 31)) | (nh << 5);
      int jb = nr0 >> 1;
      int j = jb + (lane >> 4);
      int lc = (lane & 15) ^ (j & 15);
      int nr = (j << 1) + (lc >> 3);
      async_cp16(BT + (size_t)(n0 + nr) * K + kt + (lc & 7) * 8, dst + jb * 128);
    }
  };

  int nt = K >> 6;                        // 48 for both GEMMs (>=3 required)
  unsigned short* Abuf[2] = { AsL, AsL + 16384 };
  unsigned short* Bbuf[2] = { BsL, BsL + 16384 };

  // prologue: sigma order = steady-state issue order
  stageA(Abuf[0], 0, 0);  stageB(Bbuf[0], 0, 0);
  stageB(Bbuf[0], 0, 1);  stageA(Abuf[0], 0, 1);
  stageA(Abuf[1], 64, 0); stageB(Bbuf[1], 64, 0);
  VMW6; barrier_raw();

  for (int t = 0; t < nt; t++){
    unsigned short* Ab = Abuf[t & 1];
    unsigned short* Bb = Bbuf[t & 1];
    unsigned short* An = Abuf[(t & 1) ^ 1];
    unsigned short* Bn = Bbuf[(t & 1) ^ 1];
    bool s1 = (t + 1 < nt), s2 = (t + 2 < nt);

    // q0: reads Aq0(t),Bq0(t) [covered by vmcnt@q3(t-1)]
    lda(Ab, 0); ldb(Bb, b0, 0);
    if (s1) stageB(Bn, (t + 1) << 6, 1);
    if (t == nt - 1) VMW2;
    barrier_raw();
    mfmaQ(0, b0, 0);

    // q1: reads Bq1(t) [covered by vmcnt@q3(t-1)]
    ldb(Bb, b1, 1);
    if (s1) stageA(An, (t + 1) << 6, 1);
    if (t == nt - 1) VMW0; else VMW6;
    barrier_raw();
    mfmaQ(0, b1, 1);

    // q2: reads Aq1(t) [covered by vmcnt@q1(t)]
    lda(Ab, 1);
    if (s2) stageA(Ab, (t + 2) << 6, 0);  // curr buf; q0-half consumed 2 phases ago
    barrier_raw();
    mfmaQ(1, b1, 1);

    // q3: register-resident (af mh1 + b0)
    if (s2) stageB(Bb, (t + 2) << 6, 0);
    if (t <= nt - 3) VMW6; else if (t == nt - 2) VMW4;
    barrier_raw();
    mfmaQ(1, b0, 0);
  }

  // epilogue
#pragma unroll
  for (int img = 0; img < 8; img++){
    int row = m0 + wr * 128 + img * 16 + quad * 4;
#pragma unroll
    for (int ing = 0; ing < 4; ing++){
      int col = n0 + wc * 64 + ing * 16 + l16;
      float bb = bias[col];
      f32x4 v = acc[img][ing];
#pragma unroll
      for (int r = 0; r < 4; r++){
        float out = v[r] + bb;
        if (OUT_BF16) ((unsigned short*)Cout)[(size_t)(row + r) * N + col] = ftob(out);
        else          ((float*)Cout)[(size_t)(row + r) * N + col] = out;
      }
    }
  }
}

// ---------------- rmsnorm (bf16-faithful) + 3D rope ----------------
__global__ __launch_bounds__(256) void k_rmsnorm_rope(const unsigned short* __restrict__ QKVr,
        const float* __restrict__ gq, const float* __restrict__ gk,
        const int* __restrict__ grid_sizes, const float* __restrict__ freqs,
        unsigned short* __restrict__ Qh, unsigned short* __restrict__ Kh){
  int row = blockIdx.x;
  int which = blockIdx.y;
  int b = row >> 11, s = row & 2047;
  const unsigned short* xrow = QKVr + (size_t)row * 9216 + which * 3072;
  const float* g = which ? gk : gq;
  unsigned short* out = which ? Kh : Qh;

  int tid = threadIdx.x, w = tid >> 6, lane = tid & 63;
  float ss = 0.f;
  for (int i = tid * 4; i < 3072; i += 1024){      // vectorized: 3x ushort4
    ushort4v v = *(const ushort4v*)(xrow + i);
    for (int j = 0; j < 4; j++){
      float f = btof(v[j]);
      ss += btof(ftob(f * f));      // ref squares in bf16
    }
  }
  for (int off = 32; off; off >>= 1) ss += __shfl_down(ss, off);
  __shared__ float red[4];
  if (lane == 0) red[w] = ss;
  __syncthreads();
  float tot = red[0] + red[1] + red[2] + red[3];
  float m = rb(tot * (1.0f / 3072.0f));
  m = rb(m + rb(1e-6f));
  float rn = rb(rsqrtf(m));

  int f = grid_sizes[b * 3], hh = grid_sizes[b * 3 + 1], ww = grid_sizes[b * 3 + 2];
  int fhw = f * hh * ww;

  for (int p = tid; p < 1536; p += 256){
    int c = p & 63, hd = p >> 6;
    int e0 = hd * 128 + 2 * c;
    uint32_t xp = *(const uint32_t*)(xrow + e0);   // 2 bf16 packed
    float2 gg = *(const float2*)(g + e0);
    float x0 = rb(btof((unsigned short)(xp & 0xffffu)) * rn) * rb(gg.x);
    float x1 = rb(btof((unsigned short)(xp >> 16)) * rn) * rb(gg.y);
    float cs = 1.f, sn = 0.f;
    if (s < fhw){
      int pos;
      if (c < 22) pos = s / (hh * ww);          // C1 = 22
      else if (c < 43) pos = (s / ww) % hh;     // C2 = 21
      else pos = s % ww;                        // C3 = 21
      float2 f2 = *(const float2*)(freqs + (pos * 64 + c) * 2);
      cs = f2.x; sn = f2.y;
    }
    float o0 = x0 * cs - x1 * sn;
    float o1 = x0 * sn + x1 * cs;
    size_t ob = ((size_t)((b * 24 + hd) * 2048 + s)) * 128 + 2 * c;
    uint32_t op = ((uint32_t)ftob(o1) << 16) | (uint32_t)ftob(o0);
    *(uint32_t*)(out + ob) = op;
  }
}

// V: token-major -> Vt[bh][d][t]   (vectorized x4 on the global side)
__global__ __launch_bounds__(256) void k_build_vt(const unsigned short* __restrict__ QKVr,
                                                  unsigned short* __restrict__ Vt){
  __shared__ unsigned short tile[64][132];   // stride 132 u16 = 264B (8B aligned rows)
  int bh = blockIdx.x;
  int b = bh / 24, h = bh % 24;
  int t0 = blockIdx.y * 64;
  for (int i = 0; i < 8; i++){
    int idx = i * 1024 + threadIdx.x * 4;    // step 4 elems
    int r = idx >> 7, c = idx & 127;
    *(ushort4v*)&tile[r][c] =
      *(const ushort4v*)&QKVr[(size_t)(b * 2048 + t0 + r) * 9216 + 6144 + h * 128 + c];
  }
  __syncthreads();
  for (int i = 0; i < 8; i++){
    int idx = i * 1024 + threadIdx.x * 4;
    int d = idx >> 6, t = idx & 63;          // t multiple of 4
    ushort4v o4 = { tile[t][d], tile[t + 1][d], tile[t + 2][d], tile[t + 3][d] };
    *(ushort4v*)&Vt[((size_t)bh * 128 + d) * 2048 + t0 + t] = o4;
  }
}

// ---------------- flash attention ----------------
// grid: x = q-tile of 128 rows (16), y = head (24), z = batch (2); 8 waves,
// 16 q-rows/wave. Swapped QK^T: sac = mfma(K,Q) = S^T, lane(quad,l16) holds
// S[k = t0+ct*16+quad*4+r][q = l16] -> softmax is per-lane over q-row l16.
// Pipeline per KV tile t: [inv: Ks(t) resident] issue Vs(t) | QK(t) |
//   lgkm0,B1 | issue Ks(t+1) | softmax(t) | vmcnt(2),B2 | PV(t) | lgkm0,vm0,B3
__global__ __launch_bounds__(512, 4) void k_attn(const unsigned short* __restrict__ Q,
              const unsigned short* __restrict__ Kt, const unsigned short* __restrict__ Vt,
              const int* __restrict__ seq_lens, unsigned short* __restrict__ Obuf){
  int qt = blockIdx.x, h = blockIdx.y, b = blockIdx.z;
  int bh = b * 24 + h;
  int tid = threadIdx.x, w = tid >> 6, lane = tid & 63;
  int quad = lane >> 4, l16 = lane & 15;
  int sl = seq_lens[b];
  int nkt = (sl + 63) >> 6;

  __shared__ __align__(16) unsigned short Ks[64 * 128];   // [t][d] swizzled (16KB)
  __shared__ __align__(16) unsigned short Vs[128 * 64];   // [d][t] swizzled (16KB)
  __shared__ __align__(16) unsigned short Ps[8][16 * 64]; // per-wave P (16KB)

  const unsigned short* Qb = Q + ((size_t)bh * 2048 + qt * 128 + w * 16) * 128;
  short8 qf[4];
  for (int ks = 0; ks < 4; ks++)
    qf[ks] = *(const short8*)(Qb + l16 * 128 + ks * 32 + quad * 8);

  f32x4 o[8] = {};
  float mrow = -1e30f, lrow = 0.f;      // per-lane: q-row = l16

  const float ksc = 0.08838834764831845f * 1.4426950408889634f;  // scale*log2e

  const unsigned short* Kg0 = Kt + (size_t)bh * 2048 * 128;
  const unsigned short* Vg0 = Vt + (size_t)bh * 128 * 2048;

  int vrow = lane >> 3;                      // Vs staging: row within 8-row group
  int vchunk = (lane & 7) ^ (vrow & 7);      // swizzled global chunk for Vs

  auto stageK = [&](int t0){
    for (int i = 0; i < 2; i++){              // 2 ops x 8 waves x 1KB = 16KB
      int rowi = w * 8 + i * 4;               // 4 rows of 256B per op
      int kchunk = l16 ^ ((rowi + quad) & 15);
      async_cp16(Kg0 + (size_t)(t0 + rowi + quad) * 128 + kchunk * 8,
                 (unsigned short*)Ks + rowi * 128);
    }
  };
  auto stageV = [&](int t0){
    for (int i = 0; i < 2; i++){              // 2 ops x 8 waves x 1KB = 16KB
      int rowi = w * 16 + i * 8;              // 8 rows of 128B per op
      async_cp16(Vg0 + (size_t)(rowi + vrow) * 2048 + t0 + vchunk * 8,
                 (unsigned short*)Vs + rowi * 64);
    }
  };

  // prologue: K(0) resident before loop
  stageK(0);
  asm volatile("s_waitcnt vmcnt(0)" ::: "memory");
  barrier_raw();

  for (int kt = 0; kt < nkt; kt++){
    int t0 = kt * 64;

    stageV(t0);                               // 2 vm ops in flight (Vs(t))

    f32x4 sac[4] = {};
    for (int ks = 0; ks < 4; ks++){
      int kcs = ((ks * 4 + quad) ^ l16) * 8;  // swizzled Ks read chunk
      short8 kf[4];
      for (int ct = 0; ct < 4; ct++)
        kf[ct] = *(const short8*)(Ks + (ct * 16 + l16) * 128 + kcs);
      __builtin_amdgcn_s_setprio(1);          // T5: pure-MFMA cluster
      for (int ct = 0; ct < 4; ct++)          // SWAPPED: S^T = K . Q^T
        sac[ct] = __builtin_amdgcn_mfma_f32_16x16x32_bf16(kf[ct], qf[ks], sac[ct], 0, 0, 0);
      __builtin_amdgcn_s_setprio(0);
    }

    asm volatile("s_waitcnt lgkmcnt(0)" ::: "memory");  // Ks reads retired
    barrier_raw();                            // B1: all waves done reading Ks(t)

    bool haveK = (kt + 1 < nkt);
    if (haveK) stageK(t0 + 64);               // +2 vm ops, fly under softmax/PV

    if (t0 + 64 > sl){                        // partial tile mask (k in-lane now)
      for (int ct = 0; ct < 4; ct++)
        for (int r = 0; r < 4; r++)
          if (t0 + ct * 16 + quad * 4 + r >= sl) sac[ct][r] = -1e30f;
    }

    // ---- one-pass softmax: lane owns q-row l16 (16 k-vals in regs) ----
    {
      f32x4 m03 = vmax4(vmax4(sac[0], sac[1]), vmax4(sac[2], sac[3]));
      float mx = fmaxf(fmaxf(m03[0], m03[1]), fmaxf(m03[2], m03[3]));
      mx = fmaxf(mx, __shfl_xor(mx, 16));
      mx = fmaxf(mx, __shfl_xor(mx, 32));
      float mnew = mrow;
      if (!__all((mx - mrow) * ksc <= 11.5f)){  // T13: defer-max, rare path
        mnew = fmaxf(mrow, mx);
        float alpha = exp2f((mrow - mnew) * ksc);
        mrow = mnew;
        lrow *= alpha;
        for (int r = 0; r < 4; r++){
          float ar = __shfl(alpha, quad * 4 + r, 16);  // alpha of q=quad*4+r
          for (int dt = 0; dt < 8; dt++) o[dt][r] *= ar;
        }
      }
      float psum = 0.f;
      for (int ct = 0; ct < 4; ct++){
        ushort4v pw;
        for (int r = 0; r < 4; r++){
          float p = exp2f((sac[ct][r] - mnew) * ksc);
          unsigned short pb = ftob(p);
          psum += btof(pb);                   // l consistent with bf16 P in PV
          pw[r] = pb;
        }
        // P[q=l16][k=ct*16+quad*4+r]: logical chunk c=ct*2+(quad>>1),
        // phys chunk = c ^ (q&7), within-chunk offset (quad&1)*4
        int cpos = (ct * 2 + (quad >> 1)) ^ (l16 & 7);
        *(ushort4v*)&Ps[w][l16 * 64 + cpos * 8 + (quad & 1) * 4] = pw;
      }
      psum += __shfl_xor(psum, 16);
      psum += __shfl_xor(psum, 32);
      lrow += psum;
    }

    // own Vs(t) loads done (Ks(t+1) stays in flight), then block-wide visible
    if (haveK) asm volatile("s_waitcnt vmcnt(2)" ::: "memory");
    else       asm volatile("s_waitcnt vmcnt(0)" ::: "memory");
    barrier_raw();                            // B2: Vs(t) visible block-wide

    asm volatile("s_waitcnt lgkmcnt(0)" ::: "memory");  // Ps writes drained (own wave)

    for (int ks = 0; ks < 2; ks++){
      int vcs = ((ks * 4 + quad) ^ (l16 & 7)) * 8;  // swizzled Vs/Ps read chunk
      short8 pf = *(const short8*)(&Ps[w][l16 * 64 + vcs]);
      for (int dh = 0; dh < 2; dh++){         // vf in halves of 4: caps regs
        short8 vf[4];
        for (int dt = 0; dt < 4; dt++)
          vf[dt] = *(const short8*)(Vs + ((dh * 4 + dt) * 16 + l16) * 64 + vcs);
        __builtin_amdgcn_s_setprio(1);        // T5: pure-MFMA cluster
        for (int dt = 0; dt < 4; dt++)
          o[dh * 4 + dt] = __builtin_amdgcn_mfma_f32_16x16x32_bf16(pf, vf[dt], o[dh * 4 + dt], 0, 0, 0);
        __builtin_amdgcn_s_setprio(0);
      }
    }

    asm volatile("s_waitcnt lgkmcnt(0)" ::: "memory");  // PV reads retired
    asm volatile("s_waitcnt vmcnt(0)" ::: "memory");    // Ks(t+1) landed (overlapped)
    barrier_raw();                            // B3: Vs free; Ks(t+1) visible
  }

  float inv = 1.0f / lrow;                    // per-lane: q-row l16
  for (int r = 0; r < 4; r++){
    float invr = __shfl(inv, quad * 4 + r, 16);  // inv of q=quad*4+r
    int s = qt * 128 + w * 16 + quad * 4 + r;
    size_t base = (size_t)(b * 2048 + s) * 3072 + h * 128;
    for (int dt = 0; dt < 8; dt++)
      Obuf[base + dt * 16 + l16] = ftob(o[dt][r] * invr);
  }
}

// ---------------- launch ----------------

extern "C" void kernel_launch(void* const* d_in, const int* in_sizes, int n_in,
                              void* d_out, int out_size, void* d_ws, size_t ws_size,
                              hipStream_t stream){
  const float* x          = (const float*)d_in[0];
  const int*   seq_lens   = (const int*)d_in[1];
  const int*   grid_sizes = (const int*)d_in[2];
  const float* freqs      = (const float*)d_in[3];
  const float* wq = (const float*)d_in[4];
  const float* bq = (const float*)d_in[5];
  const float* wk = (const float*)d_in[6];
  const float* bk = (const float*)d_in[7];
  const float* wv = (const float*)d_in[8];
  const float* bv = (const float*)d_in[9];
  const float* wo = (const float*)d_in[10];
  const float* bo = (const float*)d_in[11];
  const float* gq = (const float*)d_in[12];
  const float* gk = (const float*)d_in[13];

  char* ws = (char*)d_ws;
  unsigned short* Xb    = (unsigned short*)(ws);               // 25,165,824 B (also Obuf)
  unsigned short* WTqkv = (unsigned short*)(ws + 25165824);    // 56,623,104 B
  unsigned short* woT   = (unsigned short*)(ws + 81788928);    // 18,874,368 B
  float*          bias9 = (float*)(ws + 100663296);            //     36,864 B
  unsigned short* QKVr  = (unsigned short*)(ws + 100700160);   // 75,497,472 B
  unsigned short* Qh    = (unsigned short*)(ws + 176197632);   // 25,165,824 B
  unsigned short* Kh    = (unsigned short*)(ws + 201363456);   // 25,165,824 B
  unsigned short* Vth   = (unsigned short*)(ws + 226529280);   // 25,165,824 B
  unsigned short* Obuf  = Xb;                                  // Xb dead after QKV GEMM

  static bool s_attr = false;
  if (!s_attr){
    hipFuncSetAttribute(reinterpret_cast<const void*>(&k_gemm<true>),
                        hipFuncAttributeMaxDynamicSharedMemorySize, 131072);
    hipFuncSetAttribute(reinterpret_cast<const void*>(&k_gemm<false>),
                        hipFuncAttributeMaxDynamicSharedMemorySize, 131072);
    s_attr = true;
  }

  k_convert_x<<<12288, 256, 0, stream>>>(x, Xb);
  k_bias<<<36, 256, 0, stream>>>(bq, bk, bv, bias9);
  k_wt<<<dim3(48, 192), 256, 0, stream>>>(wq, wk, wv, wo, WTqkv, woT);
  k_gemm<true><<<dim3(36, 16), 512, 131072, stream>>>(Xb, WTqkv, bias9, QKVr, 9216, 3072);
  k_rmsnorm_rope<<<dim3(4096, 2), 256, 0, stream>>>(QKVr, gq, gk, grid_sizes, freqs, Qh, Kh);
  k_build_vt<<<dim3(48, 32), 256, 0, stream>>>(QKVr, Vth);
  k_attn<<<dim3(16, 24, 2), 512, 0, stream>>>(Qh, Kh, Vth, seq_lens, Obuf);
  k_gemm<false><<<dim3(12, 16), 512, 131072, stream>>>(Obuf, woT, bo, (float*)d_out, 3072, 3072);
}

// Round 8
// 748.647 us; speedup vs baseline: 1.3107x; 1.3107x over previous
//
#include <hip/hip_runtime.h>
#include <stdint.h>
#include <stddef.h>

// WanSelfAttention on gfx950.
// R5: XOR chunk-swizzle on LDS tiles (global-source permutation at staging).
// R6: T5 s_setprio around pure-MFMA clusters in k_attn.
// R7: k_attn 3-barrier pipeline with counted vmcnt; T13 defer-max; vec rope/vt.
// R9: swapped-operand QK^T in k_attn -> one-pass per-lane softmax. 8 waves.
// R11: k_gemm 256x256 8-phase (T3+T4), 128KB LDS dbuf. 277us, MfmaUtil 36%.
// R12 (REVERTED): deeper vmcnt pipeline + same-buffer t+2 staging spilled
//      (WRITE_SIZE +14MB scratch, MfmaUtil 22%, 448us). Lesson: a phase's own
//      vmcnt can't protect its ds_reads (issued before the wait), so R11's
//      per-phase VMW4 is already minimal for 2-buffer; 3-half-tile flight
//      costs registers we don't have. k_gemm below is R11 verbatim.

typedef __attribute__((ext_vector_type(8))) short short8;
typedef __attribute__((ext_vector_type(4))) float f32x4;
typedef __attribute__((ext_vector_type(4))) unsigned short ushort4v;
typedef __attribute__((address_space(1))) uint32_t gu32;
typedef __attribute__((address_space(3))) uint32_t lu32;

__device__ __forceinline__ float btof(unsigned short u){
  union { float f; uint32_t i; } x; x.i = ((uint32_t)u) << 16; return x.f;
}
__device__ __forceinline__ unsigned short ftob(float f){
  uint32_t u = __builtin_bit_cast(uint32_t, f);
  u += 0x7fffu + ((u >> 16) & 1u);   // RTNE (finite inputs only)
  return (unsigned short)(u >> 16);
}
__device__ __forceinline__ float rb(float f){ return btof(ftob(f)); }

__device__ __forceinline__ void async_cp16(const void* g, void* l){
  __builtin_amdgcn_global_load_lds((gu32*)g, (lu32*)l, 16, 0, 0);
}

__device__ __forceinline__ void barrier_raw(){
  asm volatile("" ::: "memory");
  __builtin_amdgcn_s_barrier();
  asm volatile("" ::: "memory");
}

__device__ __forceinline__ f32x4 vmax4(f32x4 a, f32x4 b){
  f32x4 r;
  r[0] = fmaxf(a[0], b[0]); r[1] = fmaxf(a[1], b[1]);
  r[2] = fmaxf(a[2], b[2]); r[3] = fmaxf(a[3], b[3]);
  return r;
}

#define VMW4 asm volatile("s_waitcnt vmcnt(4)" ::: "memory")
#define VMW2 asm volatile("s_waitcnt vmcnt(2)" ::: "memory")
#define VMW0 asm volatile("s_waitcnt vmcnt(0)" ::: "memory")

// ---------------- converters ----------------

__global__ __launch_bounds__(256) void k_convert_x(const float* __restrict__ x,
                                                   unsigned short* __restrict__ xb){
  int i = (blockIdx.x * 256 + threadIdx.x) * 4;
  float4 v = *(const float4*)(x + i);
  ushort4v o = { ftob(v.x), ftob(v.y), ftob(v.z), ftob(v.w) };
  *(ushort4v*)(xb + i) = o;
}

__global__ __launch_bounds__(256) void k_bias(const float* __restrict__ bq,
                                              const float* __restrict__ bk,
                                              const float* __restrict__ bv,
                                              float* __restrict__ bias9){
  int i = blockIdx.x * 256 + threadIdx.x;     // 0..9215
  const float* s = (i < 3072) ? bq : ((i < 6144) ? bk : bv);
  bias9[i] = s[i % 3072];
}

// Transpose f32 weights (K x N, row-major) into bf16 W^T (N x K) rows.
__global__ __launch_bounds__(256) void k_wt(const float* __restrict__ wq,
                                            const float* __restrict__ wk,
                                            const float* __restrict__ wv,
                                            const float* __restrict__ wo,
                                            unsigned short* __restrict__ WTqkv,
                                            unsigned short* __restrict__ woT){
  __shared__ float tile[64][65];
  int k0 = blockIdx.x * 64;
  int n0g = blockIdx.y * 64;
  const float* src; unsigned short* dst; int col0, drow0;
  if (n0g < 9216){
    int sel = n0g / 3072;
    src = (sel == 0) ? wq : ((sel == 1) ? wk : wv);
    col0 = n0g % 3072; dst = WTqkv; drow0 = n0g;
  } else { src = wo; col0 = n0g - 9216; dst = woT; drow0 = n0g - 9216; }
  for (int i = 0; i < 16; i++){
    int idx = i * 256 + threadIdx.x;
    int r = idx >> 6, c = idx & 63;
    tile[r][c] = src[(size_t)(k0 + r) * 3072 + col0 + c];
  }
  __syncthreads();
  for (int i = 0; i < 16; i++){
    int idx = i * 256 + threadIdx.x;
    int rr = idx >> 6, cc = idx & 63;
    dst[(size_t)(drow0 + rr) * 3072 + k0 + cc] = ftob(tile[cc][rr]);
  }
}

// ---------------- GEMM 256x256, BK=64, 8 waves, 8-phase (R11) ----------------
// LDS (dynamic 128KB): A[2][128 rows x 256B], B[2][128 rows x 256B].
// LDS row j holds matrix rows 2j,2j+1 as 16 chunks of 16B; chunk lc =
// (mr&1)*8 + kchunk; phys = lc ^ (j&15).
// Half-tile sets (wave-uniform consumption): A-q = rows with bit6==q, B-q =
// rows with bit5==q. Staged Aq0,Bq0,Bq1,Aq1 per tile; each phase stages one
// half-tile (2 loads/wave) and ends with vmcnt(4).
template <bool OUT_BF16>
__global__ __launch_bounds__(512, 2) void k_gemm(const unsigned short* __restrict__ A,
                                                 const unsigned short* __restrict__ BT,
                                                 const float* __restrict__ bias,
                                                 void* __restrict__ Cout, int N, int K){
  extern __shared__ unsigned short lds[];
  unsigned short* AsL = lds;              // [2][16384]
  unsigned short* BsL = lds + 32768;      // [2][16384]

  int tid = threadIdx.x;
  int w = tid >> 6, lane = tid & 63;
  int quad = lane >> 4, l16 = lane & 15;
  int wr = w >> 2, wc = w & 3;            // wave tile: rows wr*128, cols wc*64
  int m0 = blockIdx.y * 256, n0 = blockIdx.x * 256;

  f32x4 acc[8][4] = {};
  short8 af[4][2], b0[2][2], b1[2][2];

  auto lda = [&](const unsigned short* base, int mh){
#pragma unroll
    for (int im = 0; im < 4; im++)
#pragma unroll
      for (int kk = 0; kk < 2; kk++){
        int j = wr * 64 + mh * 32 + im * 8 + (l16 >> 1);
        int lc = ((l16 & 1) << 3) | (kk << 2) | quad;
        af[im][kk] = *(const short8*)(base + j * 128 + (lc ^ (j & 15)) * 8);
      }
  };
  auto ldb = [&](const unsigned short* base, short8 (&bb)[2][2], int nh){
#pragma unroll
    for (int in = 0; in < 2; in++)
#pragma unroll
      for (int kk = 0; kk < 2; kk++){
        int j = wc * 32 + nh * 16 + in * 8 + (l16 >> 1);
        int lc = ((l16 & 1) << 3) | (kk << 2) | quad;
        bb[in][kk] = *(const short8*)(base + j * 128 + (lc ^ (j & 15)) * 8);
      }
  };
  auto mfmaQ = [&](int mh, short8 (&bb)[2][2], int nh){
    __builtin_amdgcn_s_setprio(1);
#pragma unroll
    for (int im = 0; im < 4; im++)
#pragma unroll
      for (int in = 0; in < 2; in++)
#pragma unroll
        for (int kk = 0; kk < 2; kk++)
          acc[mh * 4 + im][nh * 2 + in] =
            __builtin_amdgcn_mfma_f32_16x16x32_bf16(af[im][kk], bb[in][kk],
                                                    acc[mh * 4 + im][nh * 2 + in], 0, 0, 0);
    __builtin_amdgcn_s_setprio(0);
  };

  // staging: one half-tile = 16KB = 2 ops/wave; LDS dest linear (wave-uniform
  // base), per-lane GLOBAL source pre-swizzled (rule: both-sides-or-neither).
  auto stageA = [&](unsigned short* dst, int kt, int mh){
#pragma unroll
    for (int i = 0; i < 2; i++){
      int idx0 = (w * 2 + i) * 8;
      int mr0 = (((idx0 >> 6) << 7) | (idx0 & 63)) | (mh << 6);
      int jb = mr0 >> 1;                  // 4 LDS rows per op
      int j = jb + (lane >> 4);
      int lc = (lane & 15) ^ (j & 15);
      int mr = (j << 1) + (lc >> 3);
      async_cp16(A + (size_t)(m0 + mr) * K + kt + (lc & 7) * 8, dst + jb * 128);
    }
  };
  auto stageB = [&](unsigned short* dst, int kt, int nh){
#pragma unroll
    for (int i = 0; i < 2; i++){
      int idx0 = (w * 2 + i) * 8;
      int nr0 = (((idx0 >> 5) << 6) | (idx0 & 31)) | (nh << 5);
      int jb = nr0 >> 1;
      int j = jb + (lane >> 4);
      int lc = (lane & 15) ^ (j & 15);
      int nr = (j << 1) + (lc >> 3);
      async_cp16(BT + (size_t)(n0 + nr) * K + kt + (lc & 7) * 8, dst + jb * 128);
    }
  };

  int nt = K >> 6;
  // prologue: tile 0 -> buf 0 (issue order Aq0,Bq0,Bq1,Aq1 = in-loop order)
  stageA(AsL, 0, 0); stageB(BsL, 0, 0); stageB(BsL, 0, 1); stageA(AsL, 0, 1);
  VMW4; barrier_raw();

  for (int t = 0; t < nt; t++){
    unsigned short* Asb = AsL + (t & 1) * 16384;
    unsigned short* Bsb = BsL + (t & 1) * 16384;
    unsigned short* Asn = AsL + ((t & 1) ^ 1) * 16384;
    unsigned short* Bsn = BsL + ((t & 1) ^ 1) * 16384;
    int ktn = (t + 1) << 6;
    bool more = (t + 1 < nt);

    // q0: (mh0, nh0) — needs Aq0(t), Bq0(t) [guaranteed by prev q3 vm(4)+bar]
    lda(Asb, 0); ldb(Bsb, b0, 0);
    if (more) stageA(Asn, ktn, 0);
    VMW4; barrier_raw();
    mfmaQ(0, b0, 0);
    barrier_raw();

    // q1: (mh0, nh1) — needs Bq1(t) [guaranteed by q0 vm(4)+bar]
    ldb(Bsb, b1, 1);
    if (more){ stageB(Bsn, ktn, 0); VMW4; } else VMW2;
    barrier_raw();
    mfmaQ(0, b1, 1);
    barrier_raw();

    // q2: (mh1, nh1) — needs Aq1(t) [guaranteed by q1 vm(4)+bar]
    lda(Asb, 1);
    if (more){ stageB(Bsn, ktn, 1); VMW4; } else VMW0;
    barrier_raw();
    mfmaQ(1, b1, 1);
    barrier_raw();

    // q3: (mh1, nh0) — register-resident af(mh1) + b0
    if (more){ stageA(Asn, ktn, 1); VMW4; }
    barrier_raw();
    mfmaQ(1, b0, 0);
    barrier_raw();
  }

  // epilogue
#pragma unroll
  for (int img = 0; img < 8; img++){
    int row = m0 + wr * 128 + img * 16 + quad * 4;
#pragma unroll
    for (int ing = 0; ing < 4; ing++){
      int col = n0 + wc * 64 + ing * 16 + l16;
      float bb = bias[col];
      f32x4 v = acc[img][ing];
#pragma unroll
      for (int r = 0; r < 4; r++){
        float out = v[r] + bb;
        if (OUT_BF16) ((unsigned short*)Cout)[(size_t)(row + r) * N + col] = ftob(out);
        else          ((float*)Cout)[(size_t)(row + r) * N + col] = out;
      }
    }
  }
}

// ---------------- rmsnorm (bf16-faithful) + 3D rope ----------------
__global__ __launch_bounds__(256) void k_rmsnorm_rope(const unsigned short* __restrict__ QKVr,
        const float* __restrict__ gq, const float* __restrict__ gk,
        const int* __restrict__ grid_sizes, const float* __restrict__ freqs,
        unsigned short* __restrict__ Qh, unsigned short* __restrict__ Kh){
  int row = blockIdx.x;
  int which = blockIdx.y;
  int b = row >> 11, s = row & 2047;
  const unsigned short* xrow = QKVr + (size_t)row * 9216 + which * 3072;
  const float* g = which ? gk : gq;
  unsigned short* out = which ? Kh : Qh;

  int tid = threadIdx.x, w = tid >> 6, lane = tid & 63;
  float ss = 0.f;
  for (int i = tid * 4; i < 3072; i += 1024){      // vectorized: 3x ushort4
    ushort4v v = *(const ushort4v*)(xrow + i);
    for (int j = 0; j < 4; j++){
      float f = btof(v[j]);
      ss += btof(ftob(f * f));      // ref squares in bf16
    }
  }
  for (int off = 32; off; off >>= 1) ss += __shfl_down(ss, off);
  __shared__ float red[4];
  if (lane == 0) red[w] = ss;
  __syncthreads();
  float tot = red[0] + red[1] + red[2] + red[3];
  float m = rb(tot * (1.0f / 3072.0f));
  m = rb(m + rb(1e-6f));
  float rn = rb(rsqrtf(m));

  int f = grid_sizes[b * 3], hh = grid_sizes[b * 3 + 1], ww = grid_sizes[b * 3 + 2];
  int fhw = f * hh * ww;

  for (int p = tid; p < 1536; p += 256){
    int c = p & 63, hd = p >> 6;
    int e0 = hd * 128 + 2 * c;
    uint32_t xp = *(const uint32_t*)(xrow + e0);   // 2 bf16 packed
    float2 gg = *(const float2*)(g + e0);
    float x0 = rb(btof((unsigned short)(xp & 0xffffu)) * rn) * rb(gg.x);
    float x1 = rb(btof((unsigned short)(xp >> 16)) * rn) * rb(gg.y);
    float cs = 1.f, sn = 0.f;
    if (s < fhw){
      int pos;
      if (c < 22) pos = s / (hh * ww);          // C1 = 22
      else if (c < 43) pos = (s / ww) % hh;     // C2 = 21
      else pos = s % ww;                        // C3 = 21
      float2 f2 = *(const float2*)(freqs + (pos * 64 + c) * 2);
      cs = f2.x; sn = f2.y;
    }
    float o0 = x0 * cs - x1 * sn;
    float o1 = x0 * sn + x1 * cs;
    size_t ob = ((size_t)((b * 24 + hd) * 2048 + s)) * 128 + 2 * c;
    uint32_t op = ((uint32_t)ftob(o1) << 16) | (uint32_t)ftob(o0);
    *(uint32_t*)(out + ob) = op;
  }
}

// V: token-major -> Vt[bh][d][t]   (vectorized x4 on the global side)
__global__ __launch_bounds__(256) void k_build_vt(const unsigned short* __restrict__ QKVr,
                                                  unsigned short* __restrict__ Vt){
  __shared__ unsigned short tile[64][132];   // stride 132 u16 = 264B (8B aligned rows)
  int bh = blockIdx.x;
  int b = bh / 24, h = bh % 24;
  int t0 = blockIdx.y * 64;
  for (int i = 0; i < 8; i++){
    int idx = i * 1024 + threadIdx.x * 4;    // step 4 elems
    int r = idx >> 7, c = idx & 127;
    *(ushort4v*)&tile[r][c] =
      *(const ushort4v*)&QKVr[(size_t)(b * 2048 + t0 + r) * 9216 + 6144 + h * 128 + c];
  }
  __syncthreads();
  for (int i = 0; i < 8; i++){
    int idx = i * 1024 + threadIdx.x * 4;
    int d = idx >> 6, t = idx & 63;          // t multiple of 4
    ushort4v o4 = { tile[t][d], tile[t + 1][d], tile[t + 2][d], tile[t + 3][d] };
    *(ushort4v*)&Vt[((size_t)bh * 128 + d) * 2048 + t0 + t] = o4;
  }
}

// ---------------- flash attention ----------------
// grid: x = q-tile of 128 rows (16), y = head (24), z = batch (2); 8 waves,
// 16 q-rows/wave. Swapped QK^T: sac = mfma(K,Q) = S^T, lane(quad,l16) holds
// S[k = t0+ct*16+quad*4+r][q = l16] -> softmax is per-lane over q-row l16.
// Pipeline per KV tile t: [inv: Ks(t) resident] issue Vs(t) | QK(t) |
//   lgkm0,B1 | issue Ks(t+1) | softmax(t) | vmcnt(2),B2 | PV(t) | lgkm0,vm0,B3
__global__ __launch_bounds__(512, 4) void k_attn(const unsigned short* __restrict__ Q,
              const unsigned short* __restrict__ Kt, const unsigned short* __restrict__ Vt,
              const int* __restrict__ seq_lens, unsigned short* __restrict__ Obuf){
  int qt = blockIdx.x, h = blockIdx.y, b = blockIdx.z;
  int bh = b * 24 + h;
  int tid = threadIdx.x, w = tid >> 6, lane = tid & 63;
  int quad = lane >> 4, l16 = lane & 15;
  int sl = seq_lens[b];
  int nkt = (sl + 63) >> 6;

  __shared__ __align__(16) unsigned short Ks[64 * 128];   // [t][d] swizzled (16KB)
  __shared__ __align__(16) unsigned short Vs[128 * 64];   // [d][t] swizzled (16KB)
  __shared__ __align__(16) unsigned short Ps[8][16 * 64]; // per-wave P (16KB)

  const unsigned short* Qb = Q + ((size_t)bh * 2048 + qt * 128 + w * 16) * 128;
  short8 qf[4];
  for (int ks = 0; ks < 4; ks++)
    qf[ks] = *(const short8*)(Qb + l16 * 128 + ks * 32 + quad * 8);

  f32x4 o[8] = {};
  float mrow = -1e30f, lrow = 0.f;      // per-lane: q-row = l16

  const float ksc = 0.08838834764831845f * 1.4426950408889634f;  // scale*log2e

  const unsigned short* Kg0 = Kt + (size_t)bh * 2048 * 128;
  const unsigned short* Vg0 = Vt + (size_t)bh * 128 * 2048;

  int vrow = lane >> 3;                      // Vs staging: row within 8-row group
  int vchunk = (lane & 7) ^ (vrow & 7);      // swizzled global chunk for Vs

  auto stageK = [&](int t0){
    for (int i = 0; i < 2; i++){              // 2 ops x 8 waves x 1KB = 16KB
      int rowi = w * 8 + i * 4;               // 4 rows of 256B per op
      int kchunk = l16 ^ ((rowi + quad) & 15);
      async_cp16(Kg0 + (size_t)(t0 + rowi + quad) * 128 + kchunk * 8,
                 (unsigned short*)Ks + rowi * 128);
    }
  };
  auto stageV = [&](int t0){
    for (int i = 0; i < 2; i++){              // 2 ops x 8 waves x 1KB = 16KB
      int rowi = w * 16 + i * 8;              // 8 rows of 128B per op
      async_cp16(Vg0 + (size_t)(rowi + vrow) * 2048 + t0 + vchunk * 8,
                 (unsigned short*)Vs + rowi * 64);
    }
  };

  // prologue: K(0) resident before loop
  stageK(0);
  asm volatile("s_waitcnt vmcnt(0)" ::: "memory");
  barrier_raw();

  for (int kt = 0; kt < nkt; kt++){
    int t0 = kt * 64;

    stageV(t0);                               // 2 vm ops in flight (Vs(t))

    f32x4 sac[4] = {};
    for (int ks = 0; ks < 4; ks++){
      int kcs = ((ks * 4 + quad) ^ l16) * 8;  // swizzled Ks read chunk
      short8 kf[4];
      for (int ct = 0; ct < 4; ct++)
        kf[ct] = *(const short8*)(Ks + (ct * 16 + l16) * 128 + kcs);
      __builtin_amdgcn_s_setprio(1);          // T5: pure-MFMA cluster
      for (int ct = 0; ct < 4; ct++)          // SWAPPED: S^T = K . Q^T
        sac[ct] = __builtin_amdgcn_mfma_f32_16x16x32_bf16(kf[ct], qf[ks], sac[ct], 0, 0, 0);
      __builtin_amdgcn_s_setprio(0);
    }

    asm volatile("s_waitcnt lgkmcnt(0)" ::: "memory");  // Ks reads retired
    barrier_raw();                            // B1: all waves done reading Ks(t)

    bool haveK = (kt + 1 < nkt);
    if (haveK) stageK(t0 + 64);               // +2 vm ops, fly under softmax/PV

    if (t0 + 64 > sl){                        // partial tile mask (k in-lane now)
      for (int ct = 0; ct < 4; ct++)
        for (int r = 0; r < 4; r++)
          if (t0 + ct * 16 + quad * 4 + r >= sl) sac[ct][r] = -1e30f;
    }

    // ---- one-pass softmax: lane owns q-row l16 (16 k-vals in regs) ----
    {
      f32x4 m03 = vmax4(vmax4(sac[0], sac[1]), vmax4(sac[2], sac[3]));
      float mx = fmaxf(fmaxf(m03[0], m03[1]), fmaxf(m03[2], m03[3]));
      mx = fmaxf(mx, __shfl_xor(mx, 16));
      mx = fmaxf(mx, __shfl_xor(mx, 32));
      float mnew = mrow;
      if (!__all((mx - mrow) * ksc <= 11.5f)){  // T13: defer-max, rare path
        mnew = fmaxf(mrow, mx);
        float alpha = exp2f((mrow - mnew) * ksc);
        mrow = mnew;
        lrow *= alpha;
        for (int r = 0; r < 4; r++){
          float ar = __shfl(alpha, quad * 4 + r, 16);  // alpha of q=quad*4+r
          for (int dt = 0; dt < 8; dt++) o[dt][r] *= ar;
        }
      }
      float psum = 0.f;
      for (int ct = 0; ct < 4; ct++){
        ushort4v pw;
        for (int r = 0; r < 4; r++){
          float p = exp2f((sac[ct][r] - mnew) * ksc);
          unsigned short pb = ftob(p);
          psum += btof(pb);                   // l consistent with bf16 P in PV
          pw[r] = pb;
        }
        // P[q=l16][k=ct*16+quad*4+r]: logical chunk c=ct*2+(quad>>1),
        // phys chunk = c ^ (q&7), within-chunk offset (quad&1)*4
        int cpos = (ct * 2 + (quad >> 1)) ^ (l16 & 7);
        *(ushort4v*)&Ps[w][l16 * 64 + cpos * 8 + (quad & 1) * 4] = pw;
      }
      psum += __shfl_xor(psum, 16);
      psum += __shfl_xor(psum, 32);
      lrow += psum;
    }

    // own Vs(t) loads done (Ks(t+1) stays in flight), then block-wide visible
    if (haveK) asm volatile("s_waitcnt vmcnt(2)" ::: "memory");
    else       asm volatile("s_waitcnt vmcnt(0)" ::: "memory");
    barrier_raw();                            // B2: Vs(t) visible block-wide

    asm volatile("s_waitcnt lgkmcnt(0)" ::: "memory");  // Ps writes drained (own wave)

    for (int ks = 0; ks < 2; ks++){
      int vcs = ((ks * 4 + quad) ^ (l16 & 7)) * 8;  // swizzled Vs/Ps read chunk
      short8 pf = *(const short8*)(&Ps[w][l16 * 64 + vcs]);
      for (int dh = 0; dh < 2; dh++){         // vf in halves of 4: caps regs
        short8 vf[4];
        for (int dt = 0; dt < 4; dt++)
          vf[dt] = *(const short8*)(Vs + ((dh * 4 + dt) * 16 + l16) * 64 + vcs);
        __builtin_amdgcn_s_setprio(1);        // T5: pure-MFMA cluster
        for (int dt = 0; dt < 4; dt++)
          o[dh * 4 + dt] = __builtin_amdgcn_mfma_f32_16x16x32_bf16(pf, vf[dt], o[dh * 4 + dt], 0, 0, 0);
        __builtin_amdgcn_s_setprio(0);
      }
    }

    asm volatile("s_waitcnt lgkmcnt(0)" ::: "memory");  // PV reads retired
    asm volatile("s_waitcnt vmcnt(0)" ::: "memory");    // Ks(t+1) landed (overlapped)
    barrier_raw();                            // B3: Vs free; Ks(t+1) visible
  }

  float inv = 1.0f / lrow;                    // per-lane: q-row l16
  for (int r = 0; r < 4; r++){
    float invr = __shfl(inv, quad * 4 + r, 16);  // inv of q=quad*4+r
    int s = qt * 128 + w * 16 + quad * 4 + r;
    size_t base = (size_t)(b * 2048 + s) * 3072 + h * 128;
    for (int dt = 0; dt < 8; dt++)
      Obuf[base + dt * 16 + l16] = ftob(o[dt][r] * invr);
  }
}

// ---------------- launch ----------------

extern "C" void kernel_launch(void* const* d_in, const int* in_sizes, int n_in,
                              void* d_out, int out_size, void* d_ws, size_t ws_size,
                              hipStream_t stream){
  const float* x          = (const float*)d_in[0];
  const int*   seq_lens   = (const int*)d_in[1];
  const int*   grid_sizes = (const int*)d_in[2];
  const float* freqs      = (const float*)d_in[3];
  const float* wq = (const float*)d_in[4];
  const float* bq = (const float*)d_in[5];
  const float* wk = (const float*)d_in[6];
  const float* bk = (const float*)d_in[7];
  const float* wv = (const float*)d_in[8];
  const float* bv = (const float*)d_in[9];
  const float* wo = (const float*)d_in[10];
  const float* bo = (const float*)d_in[11];
  const float* gq = (const float*)d_in[12];
  const float* gk = (const float*)d_in[13];

  char* ws = (char*)d_ws;
  unsigned short* Xb    = (unsigned short*)(ws);               // 25,165,824 B (also Obuf)
  unsigned short* WTqkv = (unsigned short*)(ws + 25165824);    // 56,623,104 B
  unsigned short* woT   = (unsigned short*)(ws + 81788928);    // 18,874,368 B
  float*          bias9 = (float*)(ws + 100663296);            //     36,864 B
  unsigned short* QKVr  = (unsigned short*)(ws + 100700160);   // 75,497,472 B
  unsigned short* Qh    = (unsigned short*)(ws + 176197632);   // 25,165,824 B
  unsigned short* Kh    = (unsigned short*)(ws + 201363456);   // 25,165,824 B
  unsigned short* Vth   = (unsigned short*)(ws + 226529280);   // 25,165,824 B
  unsigned short* Obuf  = Xb;                                  // Xb dead after QKV GEMM

  static bool s_attr = false;
  if (!s_attr){
    hipFuncSetAttribute(reinterpret_cast<const void*>(&k_gemm<true>),
                        hipFuncAttributeMaxDynamicSharedMemorySize, 131072);
    hipFuncSetAttribute(reinterpret_cast<const void*>(&k_gemm<false>),
                        hipFuncAttributeMaxDynamicSharedMemorySize, 131072);
    s_attr = true;
  }

  k_convert_x<<<12288, 256, 0, stream>>>(x, Xb);
  k_bias<<<36, 256, 0, stream>>>(bq, bk, bv, bias9);
  k_wt<<<dim3(48, 192), 256, 0, stream>>>(wq, wk, wv, wo, WTqkv, woT);
  k_gemm<true><<<dim3(36, 16), 512, 131072, stream>>>(Xb, WTqkv, bias9, QKVr, 9216, 3072);
  k_rmsnorm_rope<<<dim3(4096, 2), 256, 0, stream>>>(QKVr, gq, gk, grid_sizes, freqs, Qh, Kh);
  k_build_vt<<<dim3(48, 32), 256, 0, stream>>>(QKVr, Vth);
  k_attn<<<dim3(16, 24, 2), 512, 0, stream>>>(Qh, Kh, Vth, seq_lens, Obuf);
  k_gemm<false><<<dim3(12, 16), 512, 131072, stream>>>(Obuf, woT, bo, (float*)d_out, 3072, 3072);
}

// Round 10
// 742.380 us; speedup vs baseline: 1.3218x; 1.0084x over previous
//
#include <hip/hip_runtime.h>
#include <stdint.h>
#include <stddef.h>

// WanSelfAttention on gfx950.
// R5: XOR chunk-swizzle on LDS tiles (global-source permutation at staging).
// R6: T5 s_setprio around pure-MFMA clusters in k_attn.
// R7: k_attn counted-vmcnt pipeline; T13 defer-max; vec rope/vt.
// R9: swapped-operand QK^T in k_attn -> one-pass per-lane softmax. 8 waves.
// R11: k_gemm 256x256 8-phase (T3+T4), 128KB LDS dbuf. 272us, MfmaUtil 36%.
// R12 (REVERTED): same-buffer t+2 staging spilled (scratch +14MB, 448us).
// R13 GEMM (REVERTED): VMW6 with reads-at-top-of-phase raced — q3(t-1)'s
//      vmcnt(6) retires nothing (only 6 outstanding), so q0(t)'s ldb read
//      B0(t) before its staging write landed (absmax 0.042). Rule: a phase's
//      own vmcnt can't protect its own ds_reads. R11's VMW4 is the minimal
//      correct wait for this structure. k_gemm below is R11 verbatim.
// R13 attn (KEPT, re-audited): Ks double-buffered (64KB LDS total) -> B1
//      barrier + lgkm drain eliminated, 2 barriers/tile, K(t+1) prefetch
//      issues right after QK instead of after a block-wide barrier.

typedef __attribute__((ext_vector_type(8))) short short8;
typedef __attribute__((ext_vector_type(4))) float f32x4;
typedef __attribute__((ext_vector_type(4))) unsigned short ushort4v;
typedef __attribute__((address_space(1))) uint32_t gu32;
typedef __attribute__((address_space(3))) uint32_t lu32;

__device__ __forceinline__ float btof(unsigned short u){
  union { float f; uint32_t i; } x; x.i = ((uint32_t)u) << 16; return x.f;
}
__device__ __forceinline__ unsigned short ftob(float f){
  uint32_t u = __builtin_bit_cast(uint32_t, f);
  u += 0x7fffu + ((u >> 16) & 1u);   // RTNE (finite inputs only)
  return (unsigned short)(u >> 16);
}
__device__ __forceinline__ float rb(float f){ return btof(ftob(f)); }

__device__ __forceinline__ void async_cp16(const void* g, void* l){
  __builtin_amdgcn_global_load_lds((gu32*)g, (lu32*)l, 16, 0, 0);
}

__device__ __forceinline__ void barrier_raw(){
  asm volatile("" ::: "memory");
  __builtin_amdgcn_s_barrier();
  asm volatile("" ::: "memory");
}

__device__ __forceinline__ f32x4 vmax4(f32x4 a, f32x4 b){
  f32x4 r;
  r[0] = fmaxf(a[0], b[0]); r[1] = fmaxf(a[1], b[1]);
  r[2] = fmaxf(a[2], b[2]); r[3] = fmaxf(a[3], b[3]);
  return r;
}

#define VMW4 asm volatile("s_waitcnt vmcnt(4)" ::: "memory")
#define VMW2 asm volatile("s_waitcnt vmcnt(2)" ::: "memory")
#define VMW0 asm volatile("s_waitcnt vmcnt(0)" ::: "memory")

// ---------------- converters ----------------

__global__ __launch_bounds__(256) void k_convert_x(const float* __restrict__ x,
                                                   unsigned short* __restrict__ xb){
  int i = (blockIdx.x * 256 + threadIdx.x) * 4;
  float4 v = *(const float4*)(x + i);
  ushort4v o = { ftob(v.x), ftob(v.y), ftob(v.z), ftob(v.w) };
  *(ushort4v*)(xb + i) = o;
}

__global__ __launch_bounds__(256) void k_bias(const float* __restrict__ bq,
                                              const float* __restrict__ bk,
                                              const float* __restrict__ bv,
                                              float* __restrict__ bias9){
  int i = blockIdx.x * 256 + threadIdx.x;     // 0..9215
  const float* s = (i < 3072) ? bq : ((i < 6144) ? bk : bv);
  bias9[i] = s[i % 3072];
}

// Transpose f32 weights (K x N, row-major) into bf16 W^T (N x K) rows.
__global__ __launch_bounds__(256) void k_wt(const float* __restrict__ wq,
                                            const float* __restrict__ wk,
                                            const float* __restrict__ wv,
                                            const float* __restrict__ wo,
                                            unsigned short* __restrict__ WTqkv,
                                            unsigned short* __restrict__ woT){
  __shared__ float tile[64][65];
  int k0 = blockIdx.x * 64;
  int n0g = blockIdx.y * 64;
  const float* src; unsigned short* dst; int col0, drow0;
  if (n0g < 9216){
    int sel = n0g / 3072;
    src = (sel == 0) ? wq : ((sel == 1) ? wk : wv);
    col0 = n0g % 3072; dst = WTqkv; drow0 = n0g;
  } else { src = wo; col0 = n0g - 9216; dst = woT; drow0 = n0g - 9216; }
  for (int i = 0; i < 16; i++){
    int idx = i * 256 + threadIdx.x;
    int r = idx >> 6, c = idx & 63;
    tile[r][c] = src[(size_t)(k0 + r) * 3072 + col0 + c];
  }
  __syncthreads();
  for (int i = 0; i < 16; i++){
    int idx = i * 256 + threadIdx.x;
    int rr = idx >> 6, cc = idx & 63;
    dst[(size_t)(drow0 + rr) * 3072 + k0 + cc] = ftob(tile[cc][rr]);
  }
}

// ---------------- GEMM 256x256, BK=64, 8 waves, 8-phase (R11 verbatim) ------
// LDS (dynamic 128KB): A[2][128 rows x 256B], B[2][128 rows x 256B].
// LDS row j holds matrix rows 2j,2j+1 as 16 chunks of 16B; chunk lc =
// (mr&1)*8 + kchunk; phys = lc ^ (j&15).
// Half-tile sets (wave-uniform consumption): A-q = rows with bit6==q, B-q =
// rows with bit5==q. Staged Aq0,Bq0,Bq1,Aq1 per tile; each phase stages one
// half-tile (2 loads/wave) and ends with vmcnt(4) -> every read is covered
// by a wait in an EARLIER phase (2-phase retire distance).
template <bool OUT_BF16>
__global__ __launch_bounds__(512, 2) void k_gemm(const unsigned short* __restrict__ A,
                                                 const unsigned short* __restrict__ BT,
                                                 const float* __restrict__ bias,
                                                 void* __restrict__ Cout, int N, int K){
  extern __shared__ unsigned short lds[];
  unsigned short* AsL = lds;              // [2][16384]
  unsigned short* BsL = lds + 32768;      // [2][16384]

  int tid = threadIdx.x;
  int w = tid >> 6, lane = tid & 63;
  int quad = lane >> 4, l16 = lane & 15;
  int wr = w >> 2, wc = w & 3;            // wave tile: rows wr*128, cols wc*64
  int m0 = blockIdx.y * 256, n0 = blockIdx.x * 256;

  f32x4 acc[8][4] = {};
  short8 af[4][2], b0[2][2], b1[2][2];

  auto lda = [&](const unsigned short* base, int mh){
#pragma unroll
    for (int im = 0; im < 4; im++)
#pragma unroll
      for (int kk = 0; kk < 2; kk++){
        int j = wr * 64 + mh * 32 + im * 8 + (l16 >> 1);
        int lc = ((l16 & 1) << 3) | (kk << 2) | quad;
        af[im][kk] = *(const short8*)(base + j * 128 + (lc ^ (j & 15)) * 8);
      }
  };
  auto ldb = [&](const unsigned short* base, short8 (&bb)[2][2], int nh){
#pragma unroll
    for (int in = 0; in < 2; in++)
#pragma unroll
      for (int kk = 0; kk < 2; kk++){
        int j = wc * 32 + nh * 16 + in * 8 + (l16 >> 1);
        int lc = ((l16 & 1) << 3) | (kk << 2) | quad;
        bb[in][kk] = *(const short8*)(base + j * 128 + (lc ^ (j & 15)) * 8);
      }
  };
  auto mfmaQ = [&](int mh, short8 (&bb)[2][2], int nh){
    __builtin_amdgcn_s_setprio(1);
#pragma unroll
    for (int im = 0; im < 4; im++)
#pragma unroll
      for (int in = 0; in < 2; in++)
#pragma unroll
        for (int kk = 0; kk < 2; kk++)
          acc[mh * 4 + im][nh * 2 + in] =
            __builtin_amdgcn_mfma_f32_16x16x32_bf16(af[im][kk], bb[in][kk],
                                                    acc[mh * 4 + im][nh * 2 + in], 0, 0, 0);
    __builtin_amdgcn_s_setprio(0);
  };

  // staging: one half-tile = 16KB = 2 ops/wave; LDS dest linear (wave-uniform
  // base), per-lane GLOBAL source pre-swizzled (rule: both-sides-or-neither).
  auto stageA = [&](unsigned short* dst, int kt, int mh){
#pragma unroll
    for (int i = 0; i < 2; i++){
      int idx0 = (w * 2 + i) * 8;
      int mr0 = (((idx0 >> 6) << 7) | (idx0 & 63)) | (mh << 6);
      int jb = mr0 >> 1;                  // 4 LDS rows per op
      int j = jb + (lane >> 4);
      int lc = (lane & 15) ^ (j & 15);
      int mr = (j << 1) + (lc >> 3);
      async_cp16(A + (size_t)(m0 + mr) * K + kt + (lc & 7) * 8, dst + jb * 128);
    }
  };
  auto stageB = [&](unsigned short* dst, int kt, int nh){
#pragma unroll
    for (int i = 0; i < 2; i++){
      int idx0 = (w * 2 + i) * 8;
      int nr0 = (((idx0 >> 5) << 6) | (idx0 & 31)) | (nh << 5);
      int jb = nr0 >> 1;
      int j = jb + (lane >> 4);
      int lc = (lane & 15) ^ (j & 15);
      int nr = (j << 1) + (lc >> 3);
      async_cp16(BT + (size_t)(n0 + nr) * K + kt + (lc & 7) * 8, dst + jb * 128);
    }
  };

  int nt = K >> 6;
  // prologue: tile 0 -> buf 0 (issue order Aq0,Bq0,Bq1,Aq1 = in-loop order)
  stageA(AsL, 0, 0); stageB(BsL, 0, 0); stageB(BsL, 0, 1); stageA(AsL, 0, 1);
  VMW4; barrier_raw();

  for (int t = 0; t < nt; t++){
    unsigned short* Asb = AsL + (t & 1) * 16384;
    unsigned short* Bsb = BsL + (t & 1) * 16384;
    unsigned short* Asn = AsL + ((t & 1) ^ 1) * 16384;
    unsigned short* Bsn = BsL + ((t & 1) ^ 1) * 16384;
    int ktn = (t + 1) << 6;
    bool more = (t + 1 < nt);

    // q0: (mh0, nh0) — needs Aq0(t), Bq0(t) [guaranteed by prev q3 vm(4)+bar]
    lda(Asb, 0); ldb(Bsb, b0, 0);
    if (more) stageA(Asn, ktn, 0);
    VMW4; barrier_raw();
    mfmaQ(0, b0, 0);
    barrier_raw();

    // q1: (mh0, nh1) — needs Bq1(t) [guaranteed by q0 vm(4)+bar]
    ldb(Bsb, b1, 1);
    if (more){ stageB(Bsn, ktn, 0); VMW4; } else VMW2;
    barrier_raw();
    mfmaQ(0, b1, 1);
    barrier_raw();

    // q2: (mh1, nh1) — needs Aq1(t) [guaranteed by q1 vm(4)+bar]
    lda(Asb, 1);
    if (more){ stageB(Bsn, ktn, 1); VMW4; } else VMW0;
    barrier_raw();
    mfmaQ(1, b1, 1);
    barrier_raw();

    // q3: (mh1, nh0) — register-resident af(mh1) + b0
    if (more){ stageA(Asn, ktn, 1); VMW4; }
    barrier_raw();
    mfmaQ(1, b0, 0);
    barrier_raw();
  }

  // epilogue
#pragma unroll
  for (int img = 0; img < 8; img++){
    int row = m0 + wr * 128 + img * 16 + quad * 4;
#pragma unroll
    for (int ing = 0; ing < 4; ing++){
      int col = n0 + wc * 64 + ing * 16 + l16;
      float bb = bias[col];
      f32x4 v = acc[img][ing];
#pragma unroll
      for (int r = 0; r < 4; r++){
        float out = v[r] + bb;
        if (OUT_BF16) ((unsigned short*)Cout)[(size_t)(row + r) * N + col] = ftob(out);
        else          ((float*)Cout)[(size_t)(row + r) * N + col] = out;
      }
    }
  }
}

// ---------------- rmsnorm (bf16-faithful) + 3D rope ----------------
__global__ __launch_bounds__(256) void k_rmsnorm_rope(const unsigned short* __restrict__ QKVr,
        const float* __restrict__ gq, const float* __restrict__ gk,
        const int* __restrict__ grid_sizes, const float* __restrict__ freqs,
        unsigned short* __restrict__ Qh, unsigned short* __restrict__ Kh){
  int row = blockIdx.x;
  int which = blockIdx.y;
  int b = row >> 11, s = row & 2047;
  const unsigned short* xrow = QKVr + (size_t)row * 9216 + which * 3072;
  const float* g = which ? gk : gq;
  unsigned short* out = which ? Kh : Qh;

  int tid = threadIdx.x, w = tid >> 6, lane = tid & 63;
  float ss = 0.f;
  for (int i = tid * 4; i < 3072; i += 1024){      // vectorized: 3x ushort4
    ushort4v v = *(const ushort4v*)(xrow + i);
    for (int j = 0; j < 4; j++){
      float f = btof(v[j]);
      ss += btof(ftob(f * f));      // ref squares in bf16
    }
  }
  for (int off = 32; off; off >>= 1) ss += __shfl_down(ss, off);
  __shared__ float red[4];
  if (lane == 0) red[w] = ss;
  __syncthreads();
  float tot = red[0] + red[1] + red[2] + red[3];
  float m = rb(tot * (1.0f / 3072.0f));
  m = rb(m + rb(1e-6f));
  float rn = rb(rsqrtf(m));

  int f = grid_sizes[b * 3], hh = grid_sizes[b * 3 + 1], ww = grid_sizes[b * 3 + 2];
  int fhw = f * hh * ww;

  for (int p = tid; p < 1536; p += 256){
    int c = p & 63, hd = p >> 6;
    int e0 = hd * 128 + 2 * c;
    uint32_t xp = *(const uint32_t*)(xrow + e0);   // 2 bf16 packed
    float2 gg = *(const float2*)(g + e0);
    float x0 = rb(btof((unsigned short)(xp & 0xffffu)) * rn) * rb(gg.x);
    float x1 = rb(btof((unsigned short)(xp >> 16)) * rn) * rb(gg.y);
    float cs = 1.f, sn = 0.f;
    if (s < fhw){
      int pos;
      if (c < 22) pos = s / (hh * ww);          // C1 = 22
      else if (c < 43) pos = (s / ww) % hh;     // C2 = 21
      else pos = s % ww;                        // C3 = 21
      float2 f2 = *(const float2*)(freqs + (pos * 64 + c) * 2);
      cs = f2.x; sn = f2.y;
    }
    float o0 = x0 * cs - x1 * sn;
    float o1 = x0 * sn + x1 * cs;
    size_t ob = ((size_t)((b * 24 + hd) * 2048 + s)) * 128 + 2 * c;
    uint32_t op = ((uint32_t)ftob(o1) << 16) | (uint32_t)ftob(o0);
    *(uint32_t*)(out + ob) = op;
  }
}

// V: token-major -> Vt[bh][d][t]   (vectorized x4 on the global side)
__global__ __launch_bounds__(256) void k_build_vt(const unsigned short* __restrict__ QKVr,
                                                  unsigned short* __restrict__ Vt){
  __shared__ unsigned short tile[64][132];   // stride 132 u16 = 264B (8B aligned rows)
  int bh = blockIdx.x;
  int b = bh / 24, h = bh % 24;
  int t0 = blockIdx.y * 64;
  for (int i = 0; i < 8; i++){
    int idx = i * 1024 + threadIdx.x * 4;    // step 4 elems
    int r = idx >> 7, c = idx & 127;
    *(ushort4v*)&tile[r][c] =
      *(const ushort4v*)&QKVr[(size_t)(b * 2048 + t0 + r) * 9216 + 6144 + h * 128 + c];
  }
  __syncthreads();
  for (int i = 0; i < 8; i++){
    int idx = i * 1024 + threadIdx.x * 4;
    int d = idx >> 6, t = idx & 63;          // t multiple of 4
    ushort4v o4 = { tile[t][d], tile[t + 1][d], tile[t + 2][d], tile[t + 3][d] };
    *(ushort4v*)&Vt[((size_t)bh * 128 + d) * 2048 + t0 + t] = o4;
  }
}

// ---------------- flash attention ----------------
// grid: x = q-tile of 128 rows (16), y = head (24), z = batch (2); 8 waves,
// 16 q-rows/wave. Swapped QK^T: sac = mfma(K,Q) = S^T, lane(quad,l16) holds
// S[k = t0+ct*16+quad*4+r][q = l16] -> softmax is per-lane over q-row l16.
// Pipeline (Ks double-buffered, 2 barriers/tile):
//   [inv: Ks[cur](t) resident] issue Vs(t) | QK(t) | issue Ks[cur^1](t+1) |
//   softmax(t) | vmcnt(2),Ba | PV(t) | lgkm0,vmcnt(0),Bb
__global__ __launch_bounds__(512, 4) void k_attn(const unsigned short* __restrict__ Q,
              const unsigned short* __restrict__ Kt, const unsigned short* __restrict__ Vt,
              const int* __restrict__ seq_lens, unsigned short* __restrict__ Obuf){
  int qt = blockIdx.x, h = blockIdx.y, b = blockIdx.z;
  int bh = b * 24 + h;
  int tid = threadIdx.x, w = tid >> 6, lane = tid & 63;
  int quad = lane >> 4, l16 = lane & 15;
  int sl = seq_lens[b];
  int nkt = (sl + 63) >> 6;

  __shared__ __align__(16) unsigned short Ks[2][64 * 128]; // [t][d] swizzled (32KB)
  __shared__ __align__(16) unsigned short Vs[128 * 64];    // [d][t] swizzled (16KB)
  __shared__ __align__(16) unsigned short Ps[8][16 * 64];  // per-wave P (16KB)

  const unsigned short* Qb = Q + ((size_t)bh * 2048 + qt * 128 + w * 16) * 128;
  short8 qf[4];
  for (int ks = 0; ks < 4; ks++)
    qf[ks] = *(const short8*)(Qb + l16 * 128 + ks * 32 + quad * 8);

  f32x4 o[8] = {};
  float mrow = -1e30f, lrow = 0.f;      // per-lane: q-row = l16

  const float ksc = 0.08838834764831845f * 1.4426950408889634f;  // scale*log2e

  const unsigned short* Kg0 = Kt + (size_t)bh * 2048 * 128;
  const unsigned short* Vg0 = Vt + (size_t)bh * 128 * 2048;

  int vrow = lane >> 3;                      // Vs staging: row within 8-row group
  int vchunk = (lane & 7) ^ (vrow & 7);      // swizzled global chunk for Vs

  auto stageK = [&](int t0, unsigned short* dstK){
    for (int i = 0; i < 2; i++){              // 2 ops x 8 waves x 1KB = 16KB
      int rowi = w * 8 + i * 4;               // 4 rows of 256B per op
      int kchunk = l16 ^ ((rowi + quad) & 15);
      async_cp16(Kg0 + (size_t)(t0 + rowi + quad) * 128 + kchunk * 8,
                 dstK + rowi * 128);
    }
  };
  auto stageV = [&](int t0){
    for (int i = 0; i < 2; i++){              // 2 ops x 8 waves x 1KB = 16KB
      int rowi = w * 16 + i * 8;              // 8 rows of 128B per op
      async_cp16(Vg0 + (size_t)(rowi + vrow) * 2048 + t0 + vchunk * 8,
                 (unsigned short*)Vs + rowi * 64);
    }
  };

  // prologue: K(0) -> Ks[0] resident before loop
  stageK(0, &Ks[0][0]);
  VMW0;
  barrier_raw();

  for (int kt = 0; kt < nkt; kt++){
    int t0 = kt * 64;
    const unsigned short* Kc = &Ks[kt & 1][0];

    stageV(t0);                               // 2 vm ops in flight (Vs(t))

    f32x4 sac[4] = {};
    for (int ks = 0; ks < 4; ks++){
      int kcs = ((ks * 4 + quad) ^ l16) * 8;  // swizzled Ks read chunk
      short8 kf[4];
      for (int ct = 0; ct < 4; ct++)
        kf[ct] = *(const short8*)(Kc + (ct * 16 + l16) * 128 + kcs);
      __builtin_amdgcn_s_setprio(1);          // T5: pure-MFMA cluster
      for (int ct = 0; ct < 4; ct++)          // SWAPPED: S^T = K . Q^T
        sac[ct] = __builtin_amdgcn_mfma_f32_16x16x32_bf16(kf[ct], qf[ks], sac[ct], 0, 0, 0);
      __builtin_amdgcn_s_setprio(0);
    }

    bool haveK = (kt + 1 < nkt);
    if (haveK) stageK(t0 + 64, &Ks[(kt & 1) ^ 1][0]); // other buffer; its readers
                                              // retired >=2 barriers ago -> safe
                                              // to issue without a barrier here

    if (t0 + 64 > sl){                        // partial tile mask (k in-lane now)
      for (int ct = 0; ct < 4; ct++)
        for (int r = 0; r < 4; r++)
          if (t0 + ct * 16 + quad * 4 + r >= sl) sac[ct][r] = -1e30f;
    }

    // ---- one-pass softmax: lane owns q-row l16 (16 k-vals in regs) ----
    {
      f32x4 m03 = vmax4(vmax4(sac[0], sac[1]), vmax4(sac[2], sac[3]));
      float mx = fmaxf(fmaxf(m03[0], m03[1]), fmaxf(m03[2], m03[3]));
      mx = fmaxf(mx, __shfl_xor(mx, 16));
      mx = fmaxf(mx, __shfl_xor(mx, 32));
      float mnew = mrow;
      if (!__all((mx - mrow) * ksc <= 11.5f)){  // T13: defer-max, rare path
        mnew = fmaxf(mrow, mx);
        float alpha = exp2f((mrow - mnew) * ksc);
        mrow = mnew;
        lrow *= alpha;
        for (int r = 0; r < 4; r++){
          float ar = __shfl(alpha, quad * 4 + r, 16);  // alpha of q=quad*4+r
          for (int dt = 0; dt < 8; dt++) o[dt][r] *= ar;
        }
      }
      float psum = 0.f;
      for (int ct = 0; ct < 4; ct++){
        ushort4v pw;
        for (int r = 0; r < 4; r++){
          float p = exp2f((sac[ct][r] - mnew) * ksc);
          unsigned short pb = ftob(p);
          psum += btof(pb);                   // l consistent with bf16 P in PV
          pw[r] = pb;
        }
        // P[q=l16][k=ct*16+quad*4+r]: logical chunk c=ct*2+(quad>>1),
        // phys chunk = c ^ (q&7), within-chunk offset (quad&1)*4
        int cpos = (ct * 2 + (quad >> 1)) ^ (l16 & 7);
        *(ushort4v*)&Ps[w][l16 * 64 + cpos * 8 + (quad & 1) * 4] = pw;
      }
      psum += __shfl_xor(psum, 16);
      psum += __shfl_xor(psum, 32);
      lrow += psum;
    }

    // own Vs(t) loads done (Ks(t+1) stays in flight), then block-wide visible
    if (haveK) VMW2; else VMW0;
    barrier_raw();                            // Ba: Vs(t) visible block-wide

    asm volatile("s_waitcnt lgkmcnt(0)" ::: "memory");  // Ps writes drained (own wave)

    for (int ks = 0; ks < 2; ks++){
      int vcs = ((ks * 4 + quad) ^ (l16 & 7)) * 8;  // swizzled Vs/Ps read chunk
      short8 pf = *(const short8*)(&Ps[w][l16 * 64 + vcs]);
      for (int dh = 0; dh < 2; dh++){         // vf in halves of 4: caps regs
        short8 vf[4];
        for (int dt = 0; dt < 4; dt++)
          vf[dt] = *(const short8*)(Vs + ((dh * 4 + dt) * 16 + l16) * 64 + vcs);
        __builtin_amdgcn_s_setprio(1);        // T5: pure-MFMA cluster
        for (int dt = 0; dt < 4; dt++)
          o[dh * 4 + dt] = __builtin_amdgcn_mfma_f32_16x16x32_bf16(pf, vf[dt], o[dh * 4 + dt], 0, 0, 0);
        __builtin_amdgcn_s_setprio(0);
      }
    }

    asm volatile("s_waitcnt lgkmcnt(0)" ::: "memory");  // PV reads retired (Vs free)
    if (haveK) VMW0;                          // all own Ks(t+1) writes landed
    barrier_raw();                            // Bb: Ks(t+1) visible; Vs overwritable
  }

  float inv = 1.0f / lrow;                    // per-lane: q-row l16
  for (int r = 0; r < 4; r++){
    float invr = __shfl(inv, quad * 4 + r, 16);  // inv of q=quad*4+r
    int s = qt * 128 + w * 16 + quad * 4 + r;
    size_t base = (size_t)(b * 2048 + s) * 3072 + h * 128;
    for (int dt = 0; dt < 8; dt++)
      Obuf[base + dt * 16 + l16] = ftob(o[dt][r] * invr);
  }
}

// ---------------- launch ----------------

extern "C" void kernel_launch(void* const* d_in, const int* in_sizes, int n_in,
                              void* d_out, int out_size, void* d_ws, size_t ws_size,
                              hipStream_t stream){
  const float* x          = (const float*)d_in[0];
  const int*   seq_lens   = (const int*)d_in[1];
  const int*   grid_sizes = (const int*)d_in[2];
  const float* freqs      = (const float*)d_in[3];
  const float* wq = (const float*)d_in[4];
  const float* bq = (const float*)d_in[5];
  const float* wk = (const float*)d_in[6];
  const float* bk = (const float*)d_in[7];
  const float* wv = (const float*)d_in[8];
  const float* bv = (const float*)d_in[9];
  const float* wo = (const float*)d_in[10];
  const float* bo = (const float*)d_in[11];
  const float* gq = (const float*)d_in[12];
  const float* gk = (const float*)d_in[13];

  char* ws = (char*)d_ws;
  unsigned short* Xb    = (unsigned short*)(ws);               // 25,165,824 B (also Obuf)
  unsigned short* WTqkv = (unsigned short*)(ws + 25165824);    // 56,623,104 B
  unsigned short* woT   = (unsigned short*)(ws + 81788928);    // 18,874,368 B
  float*          bias9 = (float*)(ws + 100663296);            //     36,864 B
  unsigned short* QKVr  = (unsigned short*)(ws + 100700160);   // 75,497,472 B
  unsigned short* Qh    = (unsigned short*)(ws + 176197632);   // 25,165,824 B
  unsigned short* Kh    = (unsigned short*)(ws + 201363456);   // 25,165,824 B
  unsigned short* Vth   = (unsigned short*)(ws + 226529280);   // 25,165,824 B
  unsigned short* Obuf  = Xb;                                  // Xb dead after QKV GEMM

  static bool s_attr = false;
  if (!s_attr){
    hipFuncSetAttribute(reinterpret_cast<const void*>(&k_gemm<true>),
                        hipFuncAttributeMaxDynamicSharedMemorySize, 131072);
    hipFuncSetAttribute(reinterpret_cast<const void*>(&k_gemm<false>),
                        hipFuncAttributeMaxDynamicSharedMemorySize, 131072);
    s_attr = true;
  }

  k_convert_x<<<12288, 256, 0, stream>>>(x, Xb);
  k_bias<<<36, 256, 0, stream>>>(bq, bk, bv, bias9);
  k_wt<<<dim3(48, 192), 256, 0, stream>>>(wq, wk, wv, wo, WTqkv, woT);
  k_gemm<true><<<dim3(36, 16), 512, 131072, stream>>>(Xb, WTqkv, bias9, QKVr, 9216, 3072);
  k_rmsnorm_rope<<<dim3(4096, 2), 256, 0, stream>>>(QKVr, gq, gk, grid_sizes, freqs, Qh, Kh);
  k_build_vt<<<dim3(48, 32), 256, 0, stream>>>(QKVr, Vth);
  k_attn<<<dim3(16, 24, 2), 512, 0, stream>>>(Qh, Kh, Vth, seq_lens, Obuf);
  k_gemm<false><<<dim3(12, 16), 512, 131072, stream>>>(Obuf, woT, bo, (float*)d_out, 3072, 3072);
}